// Round 7
// baseline (236.898 us; speedup 1.0000x reference)
//
#include <hip/hip_runtime.h>

// out[b, c] = x[b, c] * diag[c]   for x:(8192, 4096) fp32, diag:(4096,) fp32.
// Memory-bound streaming kernel. Ideal traffic = 268.4 MB -> ~43 us at 6.3 TB/s.
//
// Round-7: FILL-MIMIC STREAMING (few long-lived blocks, long contiguous runs).
// Elimination table so far (kernel time, direct or dur-146.4 calibrated):
//   r0 1xf4/thread 32K blocks: ~77us | r3 ILP8 16MB-stride: 97.7 | r4 ILP8
//   contig 32KB: 82.5 | r5 ILP4 row/block: ~81 | r6 +nt stores: ~80.5
// -> plateau ~80us (3.3 TB/s) independent of ILP, grid, store policy.
// The 6.6 TB/s fill runs ~256 long-lived blocks streaming ~2MB contiguous
// each (9.5% occupancy); m13's 6.29 TB/s copy is the same genre. Our many
// short-lived 4-32KB streams destroy HBM row-buffer locality. This round:
//   - 1024 blocks (4/CU, ALL resident in one round, zero tail churn)
//   - each block streams a contiguous 128 KB chunk (32 float4/thread)
//   - 2-deep software pipeline: load group g+1 (8x dwordx4) while storing
//     group g -> 8 loads always in flight, stores fire-and-forget.
//   - all local-array indexing compile-time (no scratch).

typedef float f32x4 __attribute__((ext_vector_type(4)));

#define TPB 256
#define BLOCKS 1024
#define PER_THREAD 32               // N4 / (BLOCKS*TPB) = 32
#define GROUP 8
#define CHUNK (TPB * PER_THREAD)    // 8192 float4 = 128 KB per block

#define LOADG(dst, g)                                        \
    _Pragma("unroll")                                        \
    for (int j = 0; j < GROUP; ++j)                          \
        dst[j] = x[base + ((g) * GROUP + j) * TPB];

#define STOREG(src, g)                                       \
    _Pragma("unroll")                                        \
    for (int j = 0; j < GROUP; ++j)                          \
        out[base + ((g) * GROUP + j) * TPB] = src[j] * dv[j & 3];

__global__ __launch_bounds__(TPB) void diag_scale_kernel(
    const f32x4* __restrict__ x,
    const f32x4* __restrict__ d,
    f32x4* __restrict__ out)
{
    const int tid  = threadIdx.x;
    const int base = blockIdx.x * CHUNK + tid;    // chunk ≡ 0 mod 1024 cols

    // col(k) = (k*256 + tid) mod 1024 -> depends only on k&3: 4 diag regs.
    const f32x4 dv[4] = { d[tid], d[TPB + tid], d[2 * TPB + tid], d[3 * TPB + tid] };

    f32x4 a[GROUP], b[GROUP];

    LOADG(a, 0)          // group 0 in flight
    LOADG(b, 1)          // group 1 in flight
    STOREG(a, 0)         // waits only group 0 (in-order vmcnt), issues stores
    LOADG(a, 2)          // refill a while stores drain
    STOREG(b, 1)
    LOADG(b, 3)
    STOREG(a, 2)
    STOREG(b, 3)
}

extern "C" void kernel_launch(void* const* d_in, const int* in_sizes, int n_in,
                              void* d_out, int out_size, void* d_ws, size_t ws_size,
                              hipStream_t stream)
{
    const f32x4* x = (const f32x4*)d_in[0];   // (8192, 4096) fp32
    const f32x4* d = (const f32x4*)d_in[1];   // (4096,) fp32
    f32x4* out = (f32x4*)d_out;               // (8192, 4096) fp32

    diag_scale_kernel<<<BLOCKS, TPB, 0, stream>>>(x, d, out);
}

// Round 8
// 219.662 us; speedup vs baseline: 1.0785x; 1.0785x over previous
//
#include <hip/hip_runtime.h>

// out[b, c] = x[b, c] * diag[c]   for x:(8192, 4096) fp32, diag:(4096,) fp32.
// Memory-bound streaming kernel. Ideal traffic = 268.4 MB -> ~43 us at 6.3 TB/s.
//
// Round-8: r0 STRUCTURE + NONTEMPORAL LOADS (single-variable).
// Elimination table (kernel time, direct rocprof or dur-146.4 calibrated):
//   r0 1xf4/thread 32K blocks:        ~77 us   <- best, never beaten
//   r3 ILP8 16MB-stride:               97.7
//   r4 ILP8 contig 32KB/block:         82.5
//   r5 ILP4 row/block:                ~81
//   r6 r5 + nt stores:                ~80.5
//   r7 fill-mimic 1K blocks, pipeline: 81.5-82.4
// Plateau ~80 us (3.3 TB/s eff) independent of ILP, grid, contiguity, store
// policy, pipelining, occupancy. Counters show minimal traffic (FETCH 65.7 +
// WRITE 134.2 MB). Read path runs at only 0.8 TB/s at the pins while fills
// write at 6.6 -> suspect read-miss cache ALLOCATION (install in L1+L2+L3,
// evict, arbitrate vs write stream) throttles reads. x is never reused within
// a dispatch -> nt loads skip allocation; the only untested policy axis.
// Decision rule: helps -> keep; null/hurt -> revert to exact r0 and declare
// the in-harness memory floor.

typedef float f32x4 __attribute__((ext_vector_type(4)));

#define SIZE4 1024                // 4096 / 4 columns in float4 units
#define N4 8388608                // 8192 * 4096 / 4 total float4
#define TPB 256

__global__ __launch_bounds__(TPB) void diag_scale_kernel(
    const f32x4* __restrict__ x,
    const f32x4* __restrict__ d,
    f32x4* __restrict__ out)
{
    const int i = blockIdx.x * TPB + threadIdx.x;   // grid sized exactly
    const f32x4 xv = __builtin_nontemporal_load(&x[i]);
    const f32x4 dv = d[i & (SIZE4 - 1)];            // diag: regular (reused)
    out[i] = xv * dv;                               // store: regular (r6: nt null)
}

extern "C" void kernel_launch(void* const* d_in, const int* in_sizes, int n_in,
                              void* d_out, int out_size, void* d_ws, size_t ws_size,
                              hipStream_t stream)
{
    const f32x4* x = (const f32x4*)d_in[0];   // (8192, 4096) fp32
    const f32x4* d = (const f32x4*)d_in[1];   // (4096,) fp32
    f32x4* out = (f32x4*)d_out;               // (8192, 4096) fp32

    diag_scale_kernel<<<N4 / TPB, TPB, 0, stream>>>(x, d, out);
}

// Round 9
// 218.182 us; speedup vs baseline: 1.0858x; 1.0068x over previous
//
#include <hip/hip_runtime.h>

// out[b, c] = x[b, c] * diag[c]   for x:(8192, 4096) fp32, diag:(4096,) fp32.
// Memory-bound streaming kernel. Ideal traffic = 268.4 MB -> ~43 us at 6.3 TB/s.
//
// Round-9: NT LOADS + NT STORES (last untested policy combination).
// Elimination table (kernel time, direct rocprof or dur-146.4 calibrated):
//   r0 1xf4/thread 32K blocks:        ~77 us
//   r3 ILP8 16MB-stride:               97.7   (L2 set thrash)
//   r4 ILP8 contig 32KB/block:         82.5
//   r5 ILP4 row/block:                ~81
//   r6 r5 + nt stores only:           ~80.5   (null)
//   r7 fill-mimic 1K blocks+pipeline:  81.5-82.4 (null)
//   r8 r0 + nt LOADS:                 ~73.3   <- only axis that ever moved it
// Read-path cache-allocation policy is the lever; instruction-stream
// structure is not (ILP 1/4/8/32, grid 1K-32K, pipeline, occupancy: all null).
// This round adds nt on stores too: out lines stop allocating in L2/L3,
// removing read/write arbitration at the cache controllers. r2 (the only
// nt-both datapoint) was best-in-class on its structure.
// Decision rule: win -> keep; null/hurt -> revert to r8, declare in-harness
// poisoned-cache mixed-stream floor (~73 us kernel, ~3.7 TB/s effective).

typedef float f32x4 __attribute__((ext_vector_type(4)));

#define SIZE4 1024                // 4096 / 4 columns in float4 units
#define N4 8388608                // 8192 * 4096 / 4 total float4
#define TPB 256

__global__ __launch_bounds__(TPB) void diag_scale_kernel(
    const f32x4* __restrict__ x,
    const f32x4* __restrict__ d,
    f32x4* __restrict__ out)
{
    const int i = blockIdx.x * TPB + threadIdx.x;   // grid sized exactly
    const f32x4 xv = __builtin_nontemporal_load(&x[i]);
    const f32x4 dv = d[i & (SIZE4 - 1)];            // diag: regular (reused, 16 KB)
    __builtin_nontemporal_store(xv * dv, &out[i]);
}

extern "C" void kernel_launch(void* const* d_in, const int* in_sizes, int n_in,
                              void* d_out, int out_size, void* d_ws, size_t ws_size,
                              hipStream_t stream)
{
    const f32x4* x = (const f32x4*)d_in[0];   // (8192, 4096) fp32
    const f32x4* d = (const f32x4*)d_in[1];   // (4096,) fp32
    f32x4* out = (f32x4*)d_out;               // (8192, 4096) fp32

    diag_scale_kernel<<<N4 / TPB, TPB, 0, stream>>>(x, d, out);
}